// Round 10
// baseline (260.932 us; speedup 1.0000x reference)
//
#include <hip/hip_runtime.h>
#include <hip/hip_cooperative_groups.h>
#include <stdint.h>

namespace cg = cooperative_groups;

// FP32 in/out. bf16 only for MFMA operands.
// R23: collapse memset+k_pre+k_attn2+k_final (5 nodes, ~40us of boundary
// overhead by budget audit) into ONE cooperative kernel, 256x512, 2
// grid.sync()s. Phase bodies are R22's verbatim. Bonus: no atomics -> no
// memset (R16 XP/HP partial scheme, reduce measured ~free); hcomb global
// round-trip deleted (phase 2 reads hv from own block's LDS across sync).
// Ledger: R22 readlane PV (166.3 best; 4th phase-edit that didn't move
// k_attn2 off 45us -> serial latency chain, in-kernel levers exhausted);
// R21/R20/R18 concurrency levers dead (no-coresidency >64KB LDS / spill);
// R10 launch_bounds min-waves spill -- NO 2nd arg anywhere.

#define N_NODES 6144
#define GSIZE 24
#define NGRAPH 256
#define DIN 128
#define DH 64
#define EFF 512
#define EPSN 1e-5f

typedef __attribute__((ext_vector_type(8))) __bf16 bf16x8;
typedef __attribute__((ext_vector_type(4))) float f32x4;
union U16B { uint4 u; bf16x8 v; unsigned short s[8]; };

__device__ inline unsigned short f2bf(float f){
  unsigned u = __float_as_uint(f);
  u += 0x7fff + ((u>>16)&1);
  return (unsigned short)(u>>16);
}
__device__ inline float gelu_exact(float x){ return 0.5f*x*(1.0f+erff(x*0.70710678118654752f)); }

// ---- workspace float offsets ----
#define XP    0          // 256 x 256: per-graph x col sum+sumsq partials
#define HP    65536      // 256 x 128: per-graph h col partials
#define WT1   98304
#define WT2   102400
#define PWT1  106496
#define FBo   110592     // 257 floats
#define WCVT_BYTE 458752 // 3 x 512 x 128 bf16 = 393216 B

#define QSTRIDE 516      // fp32 row stride for LDS QKV (padded)
#define ARENA_HV 148608  // hv [24][68] lives here through phases 1-2
#define ARENA_A1 155136  // A1s/C1s

struct PP {
  const float *x,*wq,*bq,*wk,*bk,*wv,*bv,*nq_w,*nq_b,*nq_ms,
              *no_w,*no_b,*no_ms,*o_w1,*o_b1,*o_w2,*o_b2,
              *pn_w,*pn_b,*pn_ms,*p_w1,*p_b1,*p_w2,*p_b2;
  float *ws, *out;
};

// ---- QKV weight tile load/compute macros (R22 verbatim) ----
#define LOADW(nt, W, B) do{ \
  const int mat_ = (nt)>>2, sub_ = (nt)&3; \
  const unsigned short* wp_ = wcvt + (size_t)mat_*EFF*DIN \
      + (size_t)(h*64 + sub_*16 + m)*DIN + lq*8; \
  W[0] = *(const uint4*)(wp_);      W[1] = *(const uint4*)(wp_ + 32); \
  W[2] = *(const uint4*)(wp_ + 64); W[3] = *(const uint4*)(wp_ + 96); \
  const float* bias_ = (mat_==0) ? bq : (mat_==1) ? bk : bv; \
  B = *(const float4*)(bias_ + h*64 + sub_*16 + lq*4); \
}while(0)

#define COMPW(nt, W, B) do{ \
  f32x4 a0_ = {0.f,0.f,0.f,0.f}, a1_ = {0.f,0.f,0.f,0.f}; \
  U16B w8_; \
  w8_.u = W[0]; \
  a0_ = __builtin_amdgcn_mfma_f32_16x16x32_bf16(w8_.v, afr[0][0], a0_, 0, 0, 0); \
  a1_ = __builtin_amdgcn_mfma_f32_16x16x32_bf16(w8_.v, afr[1][0], a1_, 0, 0, 0); \
  w8_.u = W[1]; \
  a0_ = __builtin_amdgcn_mfma_f32_16x16x32_bf16(w8_.v, afr[0][1], a0_, 0, 0, 0); \
  a1_ = __builtin_amdgcn_mfma_f32_16x16x32_bf16(w8_.v, afr[1][1], a1_, 0, 0, 0); \
  w8_.u = W[2]; \
  a0_ = __builtin_amdgcn_mfma_f32_16x16x32_bf16(w8_.v, afr[0][2], a0_, 0, 0, 0); \
  a1_ = __builtin_amdgcn_mfma_f32_16x16x32_bf16(w8_.v, afr[1][2], a1_, 0, 0, 0); \
  w8_.u = W[3]; \
  a0_ = __builtin_amdgcn_mfma_f32_16x16x32_bf16(w8_.v, afr[0][3], a0_, 0, 0, 0); \
  a1_ = __builtin_amdgcn_mfma_f32_16x16x32_bf16(w8_.v, afr[1][3], a1_, 0, 0, 0); \
  const int mat_ = (nt)>>2, sub_ = (nt)&3; \
  float* dst_ = qlds + mat_*(GSIZE*QSTRIDE); \
  const int col_ = h*64 + sub_*16 + lq*4; \
  { float4 o_; o_.x=a0_[0]+B.x; o_.y=a0_[1]+B.y; o_.z=a0_[2]+B.z; o_.w=a0_[3]+B.w; \
    *(float4*)(dst_ + m*QSTRIDE + col_) = o_; } \
  if(m < 8){ float4 o_; o_.x=a1_[0]+B.x; o_.y=a1_[1]+B.y; o_.z=a1_[2]+B.z; o_.w=a1_[3]+B.w; \
    *(float4*)(dst_ + (16+m)*QSTRIDE + col_) = o_; } \
}while(0)

__global__ __launch_bounds__(512)
void k_mega(PP p){
  __shared__ __align__(16) char arena[156160];
  float* ws = p.ws;
  const float* x = p.x;
  int t = threadIdx.x, g = blockIdx.x, base = g*GSIZE;

  // ================= PHASE 0: weights cvt/transpose/fb + own-graph x-stats =
  {
    int gidx = g*512 + t;
    if(gidx < 24576){                       // bf16 cvt: 24576 chunks of 8
      int mat = gidx >> 13;
      int off = (gidx & 8191) * 8;
      const float* src = (mat==0) ? p.wq : (mat==1) ? p.wk : p.wv;
      unsigned short* dst = (unsigned short*)((char*)ws + WCVT_BYTE)
                            + (size_t)mat*EFF*DIN;
      float4 a = *(const float4*)(src + off);
      float4 b = *(const float4*)(src + off + 4);
      U16B o;
      o.s[0]=f2bf(a.x); o.s[1]=f2bf(a.y); o.s[2]=f2bf(a.z); o.s[3]=f2bf(a.w);
      o.s[4]=f2bf(b.x); o.s[5]=f2bf(b.y); o.s[6]=f2bf(b.z); o.s[7]=f2bf(b.w);
      *(uint4*)(dst + off) = o.u;
    } else if(gidx < 36864){                // transposes: 3 x 4096
      int e = gidx - 24576;
      int mat = e >> 12, q = e & 4095;
      const float* src = (mat==0) ? p.o_w1 : (mat==1) ? p.o_w2 : p.p_w1;
      float* dst = ws + ((mat==0) ? WT1 : (mat==1) ? WT2 : PWT1);
      dst[(q & 63)*64 + (q >> 6)] = src[q];
    } else if(gidx < 37121){                // fb: 257 entries
      int e = gidx - 36864;
      float v;
      if(e < 64)       v = p.o_b1[e];
      else if(e < 128) v = p.o_b2[e-64];
      else if(e < 192) v = p.p_b1[e-128];
      else if(e < 256) v = p.p_w2[e-192];
      else             v = p.p_b2[0];
      ws[FBo + e] = v;
    }
    // own-graph x col stats -> XP[g]
    float* smA = (float*)arena;
    float* smB = smA + 512;
    int c = t & 127, grp = t >> 7;
    float s = 0.f, q2 = 0.f;
    for(int r = grp*6; r < grp*6 + 6; ++r){
      float v = x[(size_t)(base + r)*DIN + c];
      s += v; q2 += v*v;
    }
    smA[t] = s; smB[t] = q2;
    __syncthreads();
    if(t < 128){
      ws[XP + g*256 + t]       = smA[t] + smA[t+128] + smA[t+256] + smA[t+384];
      ws[XP + g*256 + 128 + t] = smB[t] + smB[t+128] + smB[t+256] + smB[t+384];
    }
  }
  cg::this_grid().sync();

  // ================= PHASE 1: attention (R22 body) =================
  float* qlds = (float*)arena;
  float (*hv)[68] = (float(*)[68])(arena + ARENA_HV);
  float* A1s = (float*)(arena + ARENA_A1);
  float* C1s = A1s + 128;
  const unsigned short* wcvt = (const unsigned short*)((const char*)ws + WCVT_BYTE);
  const float *bq = p.bq, *bk = p.bk, *bv = p.bv;
  int h = t >> 6, l = t & 63;

  for(int i = t; i < GSIZE*68; i += 512) ((float*)hv)[i] = 0.f;

  // XP reduce -> A1s/C1s (redA aliases qlds start; dead before GEMM writes)
  {
    float* redA = qlds; float* redB = qlds + 512;
    int c = t & 127, grp = t >> 7;
    float s = 0.f, q = 0.f;
    for(int pp = grp*64; pp < grp*64 + 64; ++pp){
      s += ws[XP + pp*256 + c];
      q += ws[XP + pp*256 + 128 + c];
    }
    redA[t] = s; redB[t] = q;
    __syncthreads();
    if(t < 128){
      float s1 = redA[t] + redA[t+128] + redA[t+256] + redA[t+384];
      float q1 = redB[t] + redB[t+128] + redB[t+256] + redB[t+384];
      float mean = s1 * (1.0f / N_NODES);
      float ex2  = q1 * (1.0f / N_NODES);
      float cm   = mean * p.nq_ms[t];
      float var  = ex2 - 2.f*cm*mean + cm*cm;
      float rstd = rsqrtf(var + EPSN);
      float a    = p.nq_w[t] * rstd;
      A1s[t] = a; C1s[t] = p.nq_b[t] - a*cm;
    }
    __syncthreads();
  }

  int m = l & 15, lq = l >> 4;

  bf16x8 afr[2][4];
  #pragma unroll
  for(int mt = 0; mt < 2; ++mt){
    int row = mt*16 + m; if(row > GSIZE-1) row = GSIZE-1;
    const float* xr = x + (size_t)(base + row)*DIN;
    #pragma unroll
    for(int kk = 0; kk < 4; ++kk){
      int k0 = kk*32 + lq*8;
      float4 a = *(const float4*)(xr + k0);
      float4 b = *(const float4*)(xr + k0 + 4);
      U16B u;
      u.s[0] = f2bf(a.x*A1s[k0+0] + C1s[k0+0]);
      u.s[1] = f2bf(a.y*A1s[k0+1] + C1s[k0+1]);
      u.s[2] = f2bf(a.z*A1s[k0+2] + C1s[k0+2]);
      u.s[3] = f2bf(a.w*A1s[k0+3] + C1s[k0+3]);
      u.s[4] = f2bf(b.x*A1s[k0+4] + C1s[k0+4]);
      u.s[5] = f2bf(b.y*A1s[k0+5] + C1s[k0+5]);
      u.s[6] = f2bf(b.z*A1s[k0+6] + C1s[k0+6]);
      u.s[7] = f2bf(b.w*A1s[k0+7] + C1s[k0+7]);
      afr[mt][kk] = u.v;
    }
  }

  {
    uint4 wA[4], wB[4], wC[4];
    float4 bA, bB, bC;
    LOADW(0, wA, bA);  LOADW(1, wB, bB);
    LOADW(2, wC, bC);  COMPW(0, wA, bA);
    LOADW(3, wA, bA);  COMPW(1, wB, bB);
    LOADW(4, wB, bB);  COMPW(2, wC, bC);
    LOADW(5, wC, bC);  COMPW(3, wA, bA);
    LOADW(6, wA, bA);  COMPW(4, wB, bB);
    LOADW(7, wB, bB);  COMPW(5, wC, bC);
    LOADW(8, wC, bC);  COMPW(6, wA, bA);
    LOADW(9, wA, bA);  COMPW(7, wB, bB);
    LOADW(10, wB, bB); COMPW(8, wC, bC);
    LOADW(11, wC, bC); COMPW(9, wA, bA);
    COMPW(10, wB, bB);
    COMPW(11, wC, bC);
  }
  // NO barrier: wave h reads only its own columns from here on.

  float pr[3][3];
  {
    int r0 = 3*(l >> 3), j0 = 3*(l & 7);
    const float* qp = qlds + r0*QSTRIDE + h*64;
    const float* kp = qlds + GSIZE*QSTRIDE + j0*QSTRIDE + h*64;
    float s00=0.f,s01=0.f,s02=0.f,s10=0.f,s11=0.f,s12=0.f,s20=0.f,s21=0.f,s22=0.f;
    #pragma unroll
    for(int d4 = 0; d4 < 16; ++d4){
      float4 q0 = *(const float4*)(qp + d4*4);
      float4 q1 = *(const float4*)(qp + QSTRIDE + d4*4);
      float4 q2 = *(const float4*)(qp + 2*QSTRIDE + d4*4);
      float4 k0 = *(const float4*)(kp + d4*4);
      float4 k1 = *(const float4*)(kp + QSTRIDE + d4*4);
      float4 k2 = *(const float4*)(kp + 2*QSTRIDE + d4*4);
      s00 += q0.x*k0.x + q0.y*k0.y + q0.z*k0.z + q0.w*k0.w;
      s01 += q0.x*k1.x + q0.y*k1.y + q0.z*k1.z + q0.w*k1.w;
      s02 += q0.x*k2.x + q0.y*k2.y + q0.z*k2.z + q0.w*k2.w;
      s10 += q1.x*k0.x + q1.y*k0.y + q1.z*k0.z + q1.w*k0.w;
      s11 += q1.x*k1.x + q1.y*k1.y + q1.z*k1.z + q1.w*k1.w;
      s12 += q1.x*k2.x + q1.y*k2.y + q1.z*k2.z + q1.w*k2.w;
      s20 += q2.x*k0.x + q2.y*k0.y + q2.z*k0.z + q2.w*k0.w;
      s21 += q2.x*k1.x + q2.y*k1.y + q2.z*k1.z + q2.w*k1.w;
      s22 += q2.x*k2.x + q2.y*k2.y + q2.z*k2.z + q2.w*k2.w;
    }
    float a0, a1, a2, m0, su, inv;
    a0 = s00*0.125f; a1 = s01*0.125f; a2 = s02*0.125f;
    m0 = fmaxf(fmaxf(a0, a1), a2);
    #pragma unroll
    for(int o = 1; o < 8; o <<= 1) m0 = fmaxf(m0, __shfl_xor(m0, o, 8));
    a0 = __expf(a0-m0); a1 = __expf(a1-m0); a2 = __expf(a2-m0);
    su = a0 + a1 + a2;
    #pragma unroll
    for(int o = 1; o < 8; o <<= 1) su += __shfl_xor(su, o, 8);
    inv = 1.0f/(su + 1e-16f);
    pr[0][0] = a0*inv; pr[0][1] = a1*inv; pr[0][2] = a2*inv;
    a0 = s10*0.125f; a1 = s11*0.125f; a2 = s12*0.125f;
    m0 = fmaxf(fmaxf(a0, a1), a2);
    #pragma unroll
    for(int o = 1; o < 8; o <<= 1) m0 = fmaxf(m0, __shfl_xor(m0, o, 8));
    a0 = __expf(a0-m0); a1 = __expf(a1-m0); a2 = __expf(a2-m0);
    su = a0 + a1 + a2;
    #pragma unroll
    for(int o = 1; o < 8; o <<= 1) su += __shfl_xor(su, o, 8);
    inv = 1.0f/(su + 1e-16f);
    pr[1][0] = a0*inv; pr[1][1] = a1*inv; pr[1][2] = a2*inv;
    a0 = s20*0.125f; a1 = s21*0.125f; a2 = s22*0.125f;
    m0 = fmaxf(fmaxf(a0, a1), a2);
    #pragma unroll
    for(int o = 1; o < 8; o <<= 1) m0 = fmaxf(m0, __shfl_xor(m0, o, 8));
    a0 = __expf(a0-m0); a1 = __expf(a1-m0); a2 = __expf(a2-m0);
    su = a0 + a1 + a2;
    #pragma unroll
    for(int o = 1; o < 8; o <<= 1) su += __shfl_xor(su, o, 8);
    inv = 1.0f/(su + 1e-16f);
    pr[2][0] = a0*inv; pr[2][1] = a1*inv; pr[2][2] = a2*inv;
  }

  {
    float o24[GSIZE];
    #pragma unroll
    for(int r = 0; r < GSIZE; ++r) o24[r] = 0.f;
    const float* vp = qlds + 2*GSIZE*QSTRIDE + h*64 + l;
    #pragma unroll
    for(int j = 0; j < GSIZE; ++j){
      float v = vp[j*QSTRIDE];
      const int jg = j/3, jj = j%3;
      #pragma unroll
      for(int rg = 0; rg < 8; ++rg){
        #pragma unroll
        for(int rr = 0; rr < 3; ++rr){
          float pv = __uint_as_float(
              __builtin_amdgcn_readlane(__float_as_uint(pr[rr][jj]), rg*8 + jg));
          o24[rg*3+rr] = fmaf(pv, v, o24[rg*3+rr]);
        }
      }
    }
    #pragma unroll
    for(int r = 0; r < GSIZE; ++r) atomicAdd(&hv[r][l], o24[r]);
  }
  __syncthreads();

  // combine: head mean + residual fold, in LDS only (hv persists to phase 2)
  #pragma unroll
  for(int sl = 0; sl < 3; ++sl){
    int idx = t + sl*512;
    int r = idx >> 6, d = idx & 63;
    const float* xr = x + (size_t)(base + r)*DIN;
    hv[r][d] = hv[r][d]*0.125f + xr[d] + xr[64 + d];
  }
  __syncthreads();
  if(t < 64){
    float s1 = 0.f, s2 = 0.f;
    #pragma unroll
    for(int i = 0; i < GSIZE; ++i){ float v = hv[i][t]; s1 += v; s2 += v*v; }
    ws[HP + g*128 + t]      = s1;
    ws[HP + g*128 + 64 + t] = s2;
  }
  cg::this_grid().sync();

  // ================= PHASE 2: final (R19 body, hv-in-LDS, HP reduce) ======
  {
    float* W1  = (float*)arena;
    float* W2  = (float*)(arena + 16384);
    float* PW1 = (float*)(arena + 32768);
    float* fbs = (float*)(arena + 49152);
    float (*hs)[68] = (float(*)[68])(arena + ARENA_HV);   // = phase-1 hv
    float (*hn)[68] = (float(*)[68])(arena + 50192);
    float (*ts)[68] = (float(*)[68])(arena + 56720);
    float* A2s = (float*)(arena + 63248);
    float* C2s = (float*)(arena + 63504);
    float* a3  = (float*)(arena + 63760);
    float* c3  = (float*)(arena + 64016);
    float* scores = (float*)(arena + 64272);
    float* wsm = (float*)(arena + 64368);
    float* redA = (float*)(arena + 64464);
    float* redB = (float*)(arena + 66512);

    int c = t & 63, i0 = t >> 6;      // rows i0+8r, r=0..2

    // stage weights + fb + HP reduce (one phase)
    {
      const float4* s1p = (const float4*)(ws + WT1);
      const float4* s2p = (const float4*)(ws + WT2);
      const float4* s3p = (const float4*)(ws + PWT1);
      #pragma unroll
      for(int it = 0; it < 2; ++it){
        int i = t + it*512;
        ((float4*)W1)[i]  = s1p[i];
        ((float4*)W2)[i]  = s2p[i];
        ((float4*)PW1)[i] = s3p[i];
      }
      if(t < 257) fbs[t] = ws[FBo + t];
      int g8 = t >> 6;
      float r1 = 0.f, r2 = 0.f;
      for(int pp = g8*32; pp < g8*32 + 32; ++pp){
        r1 += ws[HP + pp*128 + c];
        r2 += ws[HP + pp*128 + 64 + c];
      }
      redA[t] = r1; redB[t] = r2;
    }
    __syncthreads();
    if(t < DH){
      float a1 = redA[t]+redA[t+64]+redA[t+128]+redA[t+192]
               + redA[t+256]+redA[t+320]+redA[t+384]+redA[t+448];
      float a2 = redB[t]+redB[t+64]+redB[t+128]+redB[t+192]
               + redB[t+256]+redB[t+320]+redB[t+384]+redB[t+448];
      float mean = a1 * (1.0f / N_NODES);
      float ex2  = a2 * (1.0f / N_NODES);
      float cm   = mean * p.no_ms[t];
      float var  = ex2 - 2.f*cm*mean + cm*cm;
      float rstd = rsqrtf(var + EPSN);
      float a    = p.no_w[t] * rstd;
      A2s[t] = a; C2s[t] = p.no_b[t] - a*cm;
    }
    __syncthreads();
    {
      float a2 = A2s[c], c2v = C2s[c];
      #pragma unroll
      for(int r = 0; r < 3; ++r){
        int i = i0 + 8*r;
        hn[i][c] = a2*hs[i][c] + c2v;
      }
    }
    __syncthreads();

    {
      float acc[3];
      #pragma unroll
      for(int r = 0; r < 3; ++r) acc[r] = fbs[c];
      #pragma unroll 16
      for(int k = 0; k < DH; ++k){
        float w = W1[k*DH + c];
        #pragma unroll
        for(int r = 0; r < 3; ++r) acc[r] = fmaf(hn[i0 + 8*r][k], w, acc[r]);
      }
      #pragma unroll
      for(int r = 0; r < 3; ++r) ts[i0 + 8*r][c] = gelu_exact(acc[r]);
    }
    __syncthreads();

    {
      float acc[3];
      #pragma unroll
      for(int r = 0; r < 3; ++r) acc[r] = fbs[64 + c];
      #pragma unroll 16
      for(int k = 0; k < DH; ++k){
        float w = W2[k*DH + c];
        #pragma unroll
        for(int r = 0; r < 3; ++r) acc[r] = fmaf(ts[i0 + 8*r][k], w, acc[r]);
      }
      #pragma unroll
      for(int r = 0; r < 3; ++r) hs[i0 + 8*r][c] += acc[r];
    }
    __syncthreads();

    if(t < DH){
      float s1 = 0.f, s2 = 0.f;
      #pragma unroll
      for(int i = 0; i < GSIZE; i++){ float v = hs[i][t]; s1 += v; s2 += v*v; }
      float mean = s1 * (1.0f / GSIZE);
      float ex2  = s2 * (1.0f / GSIZE);
      float cm   = mean * p.pn_ms[t];
      float var  = ex2 - 2.f*cm*mean + cm*cm;
      float rstd = rsqrtf(var + EPSN);
      float a    = p.pn_w[t] * rstd;
      a3[t] = a; c3[t] = p.pn_b[t] - a*cm;
    }
    __syncthreads();

    {
      float acc[3];
      #pragma unroll
      for(int r = 0; r < 3; ++r) acc[r] = fbs[128 + c];
      #pragma unroll 16
      for(int k = 0; k < DH; ++k){
        float w  = PW1[k*DH + c];
        float ak = a3[k], ck = c3[k];
        #pragma unroll
        for(int r = 0; r < 3; ++r){
          float hnv = fmaf(ak, hs[i0 + 8*r][k], ck);
          acc[r] = fmaf(hnv, w, acc[r]);
        }
      }
      #pragma unroll
      for(int r = 0; r < 3; ++r) ts[i0 + 8*r][c] = gelu_exact(acc[r]);
    }
    __syncthreads();

    if(t < GSIZE){
      const float4* tp = (const float4*)ts[t];
      const float4* wp = (const float4*)(fbs + 192);
      float s = fbs[256];
      #pragma unroll
      for(int q = 0; q < 16; ++q){
        float4 a = tp[q], b = wp[q];
        s += a.x*b.x + a.y*b.y + a.z*b.z + a.w*b.w;
      }
      scores[t] = s;
    }
    __syncthreads();
    if(t < GSIZE){
      float mx = -1e30f;
      #pragma unroll
      for(int j = 0; j < GSIZE; j++) mx = fmaxf(mx, scores[j]);
      float sum = 0.f;
      #pragma unroll
      for(int j = 0; j < GSIZE; j++) sum += __expf(scores[j] - mx);
      wsm[t] = __expf(scores[t] - mx) / (sum + 1e-16f);
    }
    __syncthreads();
    if(t < DIN){
      float s = 0.f;
      #pragma unroll 8
      for(int i = 0; i < GSIZE; i++) s += wsm[i] * x[(size_t)(base+i)*DIN + t];
      p.out[(size_t)g*DIN + t] = s;
    }
  }
}

extern "C" void kernel_launch(void* const* d_in, const int* in_sizes, int n_in,
                              void* d_out, int out_size, void* d_ws, size_t ws_size,
                              hipStream_t stream){
  (void)in_sizes; (void)n_in; (void)out_size; (void)ws_size;
  PP prm;
  prm.x    = (const float*)d_in[0];
  prm.nq_w = (const float*)d_in[4];
  prm.nq_b = (const float*)d_in[5];
  prm.nq_ms= (const float*)d_in[6];
  prm.wq   = (const float*)d_in[7];
  prm.bq   = (const float*)d_in[8];
  prm.wk   = (const float*)d_in[9];
  prm.bk   = (const float*)d_in[10];
  prm.wv   = (const float*)d_in[11];
  prm.bv   = (const float*)d_in[12];
  prm.no_w = (const float*)d_in[13];
  prm.no_b = (const float*)d_in[14];
  prm.no_ms= (const float*)d_in[15];
  prm.o_w1 = (const float*)d_in[16];
  prm.o_b1 = (const float*)d_in[17];
  prm.o_w2 = (const float*)d_in[18];
  prm.o_b2 = (const float*)d_in[19];
  prm.pn_w = (const float*)d_in[20];
  prm.pn_b = (const float*)d_in[21];
  prm.pn_ms= (const float*)d_in[22];
  prm.p_w1 = (const float*)d_in[23];
  prm.p_b1 = (const float*)d_in[24];
  prm.p_w2 = (const float*)d_in[25];
  prm.p_b2 = (const float*)d_in[26];
  prm.ws   = (float*)d_ws;
  prm.out  = (float*)d_out;

  void* kargs[] = { &prm };
  hipLaunchCooperativeKernel((const void*)k_mega, dim3(NGRAPH), dim3(512),
                             kargs, 0, stream);
}

// Round 11
// 160.208 us; speedup vs baseline: 1.6287x; 1.6287x over previous
//
#include <hip/hip_runtime.h>
#include <stdint.h>

// FP32 in/out. bf16 only for MFMA operands.
// R24: concurrency lever retried in the regime where it can work: 1 head per
// block -> LDS 20.6KB (QKV [3][24][68] fp32 + A1C1), 2048 blocks x 256 thr
// -> ~5 blocks/CU = 5 waves/SIMD (vs 2 at 156KB). Prior occupancy failures
// were all >64KB LDS (R18 spill / R20 80KB rounding / R21 75KB still 1/CU).
// S-dots d-quartered across lane bits 4-5 (shfl_xor 16/32 combine, R18
// pattern); PV readlane (R22); cross-block hcomb atomics + k_hfix (R20).
// Ledger: R23 cooperative mega-kernel +95us (grid.sync ~35us in-kernel +
// ~100us launch path -- cooperative bypasses graph fast path); R22 readlane
// PV (166.3 best); R21/R20/R18 big-LDS concurrency dead; R10 launch_bounds
// min-waves spill -- NO 2nd arg anywhere.

#define N_NODES 6144
#define GSIZE 24
#define NGRAPH 256
#define DIN 128
#define DH 64
#define EFF 512
#define EPSN 1e-5f

typedef __attribute__((ext_vector_type(8))) __bf16 bf16x8;
typedef __attribute__((ext_vector_type(4))) float f32x4;
union U16B { uint4 u; bf16x8 v; unsigned short s[8]; };

__device__ inline unsigned short f2bf(float f){
  unsigned u = __float_as_uint(f);
  u += 0x7fff + ((u>>16)&1);
  return (unsigned short)(u>>16);
}
__device__ inline float gelu_exact(float x){ return 0.5f*x*(1.0f+erff(x*0.70710678118654752f)); }

// ---- workspace float offsets (R20 layout) ----
#define XS    0          // 256 floats: x col sum+sumsq, ATOMIC
#define HS    256        // 128 floats: h col sum+sumsq, ATOMIC
#define HCF   384        // hcomb: 6144 x 64 fp32 (atomic-accumulated), ends 393600
#define WT1   393600
#define WT2   397696
#define PWT1  401792
#define FBo   405888     // 257 floats
#define WCVT_BYTE  1703936   // 3 x 512 x 128 bf16 = 393216 B

#define QS1 68           // fp32 row stride, 1-head QKV tile

// ================= K1: k_pre (R20 verbatim) =================
__global__ __launch_bounds__(256)
void k_pre(const float* __restrict__ x,
           const float* __restrict__ o_w1, const float* __restrict__ o_w2,
           const float* __restrict__ p_w1,
           const float* __restrict__ o_b1, const float* __restrict__ o_b2,
           const float* __restrict__ p_b1, const float* __restrict__ p_w2,
           const float* __restrict__ p_b2,
           const float* __restrict__ wq, const float* __restrict__ wk,
           const float* __restrict__ wv,
           float* __restrict__ wsf){
  int t = threadIdx.x;
  int bi = blockIdx.x;
  if(bi < 192){
    int c = t & 127, h = t >> 7;
    float s = 0.f, q = 0.f;
    #pragma unroll
    for(int r = 0; r < 16; ++r){
      float v = x[(size_t)(bi*32 + h + 2*r)*DIN + c];
      s += v; q += v*v;
    }
    __shared__ float sm[256], sm2[256];
    sm[t] = s; sm2[t] = q;
    __syncthreads();
    if(t < 128){
      atomicAdd(&wsf[XS + t],       sm[t] + sm[t+128]);
      atomicAdd(&wsf[XS + 128 + t], sm2[t] + sm2[t+128]);
    }
    return;
  }
  if(bi < 195){
    const float* src; float* dst;
    if(bi == 192){ src = o_w1; dst = wsf + WT1; }
    else if(bi == 193){ src = o_w2; dst = wsf + WT2; }
    else { src = p_w1; dst = wsf + PWT1; }
    for(int p = t; p < DH*DH; p += 256){
      int r = p >> 6, c = p & 63;
      dst[c*DH + r] = src[p];
    }
    if(bi == 192){
      float* fb = wsf + FBo;
      if(t < 64){
        fb[t]       = o_b1[t];
        fb[64 + t]  = o_b2[t];
        fb[128 + t] = p_b1[t];
        fb[192 + t] = p_w2[t];
      }
      if(t == 0) fb[256] = p_b2[0];
    }
    return;
  }
  int j = bi - 195;               // 0..11
  int mat = j >> 2, seg = j & 3;
  const float* src = (mat==0) ? wq : (mat==1) ? wk : wv;
  unsigned short* dst = (unsigned short*)((char*)wsf + WCVT_BYTE)
                        + (size_t)mat*EFF*DIN + seg*16384;
  const float* sp = src + seg*16384;
  for(int e = t*8; e < 16384; e += 2048){
    float4 a = *(const float4*)(sp + e);
    float4 b = *(const float4*)(sp + e + 4);
    U16B o;
    o.s[0]=f2bf(a.x); o.s[1]=f2bf(a.y); o.s[2]=f2bf(a.z); o.s[3]=f2bf(a.w);
    o.s[4]=f2bf(b.x); o.s[5]=f2bf(b.y); o.s[6]=f2bf(b.z); o.s[7]=f2bf(b.w);
    *(uint4*)(dst + e) = o.u;
  }
}

// ---- QKV weight tile macros (1-head block: h = block's head) ----
#define LOADW1(nt, W, B) do{ \
  const int mat_ = (nt)>>2, sub_ = (nt)&3; \
  const unsigned short* wp_ = wcvt + (size_t)mat_*EFF*DIN \
      + (size_t)(h*64 + sub_*16 + m)*DIN + lq*8; \
  W[0] = *(const uint4*)(wp_);      W[1] = *(const uint4*)(wp_ + 32); \
  W[2] = *(const uint4*)(wp_ + 64); W[3] = *(const uint4*)(wp_ + 96); \
  const float* bias_ = (mat_==0) ? bq : (mat_==1) ? bk : bv; \
  B = *(const float4*)(bias_ + h*64 + sub_*16 + lq*4); \
}while(0)

#define COMPW1(nt, W, B) do{ \
  const int mat_ = (nt)>>2, sub_ = (nt)&3; \
  f32x4 a0_ = {0.f,0.f,0.f,0.f}, a1_ = {0.f,0.f,0.f,0.f}; \
  U16B w8_; \
  w8_.u = W[0]; \
  a0_ = __builtin_amdgcn_mfma_f32_16x16x32_bf16(w8_.v, afr[0][0], a0_, 0, 0, 0); \
  a1_ = __builtin_amdgcn_mfma_f32_16x16x32_bf16(w8_.v, afr[1][0], a1_, 0, 0, 0); \
  w8_.u = W[1]; \
  a0_ = __builtin_amdgcn_mfma_f32_16x16x32_bf16(w8_.v, afr[0][1], a0_, 0, 0, 0); \
  a1_ = __builtin_amdgcn_mfma_f32_16x16x32_bf16(w8_.v, afr[1][1], a1_, 0, 0, 0); \
  w8_.u = W[2]; \
  a0_ = __builtin_amdgcn_mfma_f32_16x16x32_bf16(w8_.v, afr[0][2], a0_, 0, 0, 0); \
  a1_ = __builtin_amdgcn_mfma_f32_16x16x32_bf16(w8_.v, afr[1][2], a1_, 0, 0, 0); \
  w8_.u = W[3]; \
  a0_ = __builtin_amdgcn_mfma_f32_16x16x32_bf16(w8_.v, afr[0][3], a0_, 0, 0, 0); \
  a1_ = __builtin_amdgcn_mfma_f32_16x16x32_bf16(w8_.v, afr[1][3], a1_, 0, 0, 0); \
  float* dst_ = qlds + mat_*(GSIZE*QS1); \
  const int col_ = sub_*16 + lq*4; \
  { float4 o_; o_.x=a0_[0]+B.x; o_.y=a0_[1]+B.y; o_.z=a0_[2]+B.z; o_.w=a0_[3]+B.w; \
    *(float4*)(dst_ + m*QS1 + col_) = o_; } \
  if(m < 8){ float4 o_; o_.x=a1_[0]+B.x; o_.y=a1_[1]+B.y; o_.z=a1_[2]+B.z; o_.w=a1_[3]+B.w; \
    *(float4*)(dst_ + (16+m)*QS1 + col_) = o_; } \
}while(0)

// ================= K2: k_attn4 =================
// 2048 blocks: block b = (graph b>>3, head b&7). 256 thr = 4 waves.
// LDS 20,608B -> ~5 blocks/CU (5 waves/SIMD). GEMM: 3 nt-tiles/wave.
// S: slot sl=l&15 (rg=sl>>3 rows w*6+rg*3.., jg=sl&7 cols jg*3..),
// d-quarter dq=l>>4, combined shfl_xor(16)+shfl_xor(32). Softmax width-8.
// PV: readlane from dq=0 replicas; *0.125 atomicAdd into zeroed hcomb.
__global__ __launch_bounds__(256)
void k_attn4(const float* __restrict__ x,
             const float* __restrict__ bq, const float* __restrict__ bk,
             const float* __restrict__ bv,
             const float* __restrict__ nq_w, const float* __restrict__ nq_b,
             const float* __restrict__ nq_ms,
             float* __restrict__ ws, float* __restrict__ hcomb){
  __shared__ __align__(16) float qlds[3*GSIZE*QS1];   // 19,584 B
  __shared__ float A1s[DIN], C1s[DIN];                // 1,024 B

  int t = threadIdx.x, b = blockIdx.x;
  int g = b >> 3, h = b & 7, base = g*GSIZE;
  int w = t >> 6, l = t & 63;
  const unsigned short* wcvt = (const unsigned short*)((const char*)ws + WCVT_BYTE);

  // ---- x-norm coeffs from atomic sums
  if(t < 128){
    float s1 = ws[XS + t];
    float q1 = ws[XS + 128 + t];
    float mean = s1 * (1.0f / N_NODES);
    float ex2  = q1 * (1.0f / N_NODES);
    float cm   = mean * nq_ms[t];
    float var  = ex2 - 2.f*cm*mean + cm*cm;
    float rstd = rsqrtf(var + EPSN);
    float a    = nq_w[t] * rstd;
    A1s[t] = a; C1s[t] = nq_b[t] - a*cm;
  }
  __syncthreads();                                    // bar1

  int m = l & 15, lq = l >> 4;

  // ---- A-fragments (xhat bf16), identical on all waves
  bf16x8 afr[2][4];
  #pragma unroll
  for(int mt = 0; mt < 2; ++mt){
    int row = mt*16 + m; if(row > GSIZE-1) row = GSIZE-1;
    const float* xr = x + (size_t)(base + row)*DIN;
    #pragma unroll
    for(int kk = 0; kk < 4; ++kk){
      int k0 = kk*32 + lq*8;
      float4 a = *(const float4*)(xr + k0);
      float4 bb = *(const float4*)(xr + k0 + 4);
      U16B u;
      u.s[0] = f2bf(a.x*A1s[k0+0] + C1s[k0+0]);
      u.s[1] = f2bf(a.y*A1s[k0+1] + C1s[k0+1]);
      u.s[2] = f2bf(a.z*A1s[k0+2] + C1s[k0+2]);
      u.s[3] = f2bf(a.w*A1s[k0+3] + C1s[k0+3]);
      u.s[4] = f2bf(bb.x*A1s[k0+4] + C1s[k0+4]);
      u.s[5] = f2bf(bb.y*A1s[k0+5] + C1s[k0+5]);
      u.s[6] = f2bf(bb.z*A1s[k0+6] + C1s[k0+6]);
      u.s[7] = f2bf(bb.w*A1s[k0+7] + C1s[k0+7]);
      afr[mt][kk] = u.v;
    }
  }

  // ---- QKV GEMM: wave w does nt tiles w*3..w*3+2 (depth-2 pipeline)
  {
    uint4 wA[4], wB[4];
    float4 bA, bB;
    int nb = w*3;
    LOADW1(nb+0, wA, bA);  LOADW1(nb+1, wB, bB);
    COMPW1(nb+0, wA, bA);  LOADW1(nb+2, wA, bA);
    COMPW1(nb+1, wB, bB);
    COMPW1(nb+2, wA, bA);
  }
  __syncthreads();                                    // bar2: QKV complete (cross-wave)

  // ---- S dots: rows w*6+(sl>>3)*3.., cols (sl&7)*3.., d-quarter dq
  float pr[3][3];
  {
    int sl = l & 15, dq = l >> 4;
    int r0 = w*6 + (sl >> 3)*3, j0 = (sl & 7)*3;
    const float* qp = qlds + r0*QS1 + dq*16;
    const float* kp = qlds + GSIZE*QS1 + j0*QS1 + dq*16;
    float s00=0.f,s01=0.f,s02=0.f,s10=0.f,s11=0.f,s12=0.f,s20=0.f,s21=0.f,s22=0.f;
    #pragma unroll
    for(int d4 = 0; d4 < 4; ++d4){
      float4 q0 = *(const float4*)(qp + d4*4);
      float4 q1 = *(const float4*)(qp + QS1 + d4*4);
      float4 q2 = *(const float4*)(qp + 2*QS1 + d4*4);
      float4 k0 = *(const float4*)(kp + d4*4);
      float4 k1 = *(const float4*)(kp + QS1 + d4*4);
      float4 k2 = *(const float4*)(kp + 2*QS1 + d4*4);
      s00 += q0.x*k0.x + q0.y*k0.y + q0.z*k0.z + q0.w*k0.w;
      s01 += q0.x*k1.x + q0.y*k1.y + q0.z*k1.z + q0.w*k1.w;
      s02 += q0.x*k2.x + q0.y*k2.y + q0.z*k2.z + q0.w*k2.w;
      s10 += q1.x*k0.x + q1.y*k0.y + q1.z*k0.z + q1.w*k0.w;
      s11 += q1.x*k1.x + q1.y*k1.y + q1.z*k1.z + q1.w*k1.w;
      s12 += q1.x*k2.x + q1.y*k2.y + q1.z*k2.z + q1.w*k2.w;
      s20 += q2.x*k0.x + q2.y*k0.y + q2.z*k0.z + q2.w*k0.w;
      s21 += q2.x*k1.x + q2.y*k1.y + q2.z*k1.z + q2.w*k1.w;
      s22 += q2.x*k2.x + q2.y*k2.y + q2.z*k2.z + q2.w*k2.w;
    }
    // combine d-quarters: (q0+q1)+(q2+q3), identical on all replicas
    s00 += __shfl_xor(s00, 16); s01 += __shfl_xor(s01, 16); s02 += __shfl_xor(s02, 16);
    s10 += __shfl_xor(s10, 16); s11 += __shfl_xor(s11, 16); s12 += __shfl_xor(s12, 16);
    s20 += __shfl_xor(s20, 16); s21 += __shfl_xor(s21, 16); s22 += __shfl_xor(s22, 16);
    s00 += __shfl_xor(s00, 32); s01 += __shfl_xor(s01, 32); s02 += __shfl_xor(s02, 32);
    s10 += __shfl_xor(s10, 32); s11 += __shfl_xor(s11, 32); s12 += __shfl_xor(s12, 32);
    s20 += __shfl_xor(s20, 32); s21 += __shfl_xor(s21, 32); s22 += __shfl_xor(s22, 32);

    // softmax rows r0..r0+2 over 24 cols (width-8 xor over jg lanes)
    float a0, a1, a2, m0, su, inv;
    a0 = s00*0.125f; a1 = s01*0.125f; a2 = s02*0.125f;
    m0 = fmaxf(fmaxf(a0, a1), a2);
    #pragma unroll
    for(int o = 1; o < 8; o <<= 1) m0 = fmaxf(m0, __shfl_xor(m0, o, 8));
    a0 = __expf(a0-m0); a1 = __expf(a1-m0); a2 = __expf(a2-m0);
    su = a0 + a1 + a2;
    #pragma unroll
    for(int o = 1; o < 8; o <<= 1) su += __shfl_xor(su, o, 8);
    inv = 1.0f/(su + 1e-16f);
    pr[0][0] = a0*inv; pr[0][1] = a1*inv; pr[0][2] = a2*inv;
    a0 = s10*0.125f; a1 = s11*0.125f; a2 = s12*0.125f;
    m0 = fmaxf(fmaxf(a0, a1), a2);
    #pragma unroll
    for(int o = 1; o < 8; o <<= 1) m0 = fmaxf(m0, __shfl_xor(m0, o, 8));
    a0 = __expf(a0-m0); a1 = __expf(a1-m0); a2 = __expf(a2-m0);
    su = a0 + a1 + a2;
    #pragma unroll
    for(int o = 1; o < 8; o <<= 1) su += __shfl_xor(su, o, 8);
    inv = 1.0f/(su + 1e-16f);
    pr[1][0] = a0*inv; pr[1][1] = a1*inv; pr[1][2] = a2*inv;
    a0 = s20*0.125f; a1 = s21*0.125f; a2 = s22*0.125f;
    m0 = fmaxf(fmaxf(a0, a1), a2);
    #pragma unroll
    for(int o = 1; o < 8; o <<= 1) m0 = fmaxf(m0, __shfl_xor(m0, o, 8));
    a0 = __expf(a0-m0); a1 = __expf(a1-m0); a2 = __expf(a2-m0);
    su = a0 + a1 + a2;
    #pragma unroll
    for(int o = 1; o < 8; o <<= 1) su += __shfl_xor(su, o, 8);
    inv = 1.0f/(su + 1e-16f);
    pr[2][0] = a0*inv; pr[2][1] = a1*inv; pr[2][2] = a2*inv;
  }

  // ---- PV: lane l = dim d; wave's 6 rows; P via readlane from dq=0 lanes
  {
    float o6[6];
    #pragma unroll
    for(int r = 0; r < 6; ++r) o6[r] = 0.f;
    const float* vp = qlds + 2*GSIZE*QS1 + l;
    #pragma unroll
    for(int j = 0; j < GSIZE; ++j){
      float v = vp[j*QS1];
      const int jg = j/3, jj = j%3;                 // constants after unroll
      #pragma unroll
      for(int a = 0; a < 2; ++a){
        #pragma unroll
        for(int rr = 0; rr < 3; ++rr){
          float pv = __uint_as_float(
              __builtin_amdgcn_readlane(__float_as_uint(pr[rr][jj]), a*8 + jg));
          o6[a*3+rr] = fmaf(pv, v, o6[a*3+rr]);
        }
      }
    }
    #pragma unroll
    for(int a = 0; a < 2; ++a)
      #pragma unroll
      for(int rr = 0; rr < 3; ++rr)
        atomicAdd(&hcomb[(size_t)(base + w*6 + a*3 + rr)*DH + l],
                  o6[a*3+rr]*0.125f);
  }
}

// ================= K2.5: k_hfix (R20 verbatim) =================
__global__ __launch_bounds__(256)
void k_hfix(const float* __restrict__ x, float* __restrict__ ws,
            float* __restrict__ hcomb){
  __shared__ float redA[256], redB[256];
  int t = threadIdx.x, b = blockIdx.x;
  int d = t & 63, rg = t >> 6;
  int r0 = b*32 + rg*8;
  float s1 = 0.f, s2 = 0.f;
  #pragma unroll
  for(int k = 0; k < 8; ++k){
    int r = r0 + k;
    const float* xr = x + (size_t)r*DIN;
    float v = hcomb[(size_t)r*DH + d] + xr[d] + xr[64 + d];
    hcomb[(size_t)r*DH + d] = v;
    s1 += v; s2 += v*v;
  }
  redA[t] = s1; redB[t] = s2;
  __syncthreads();
  if(t < 64){
    float a1 = redA[t] + redA[t+64] + redA[t+128] + redA[t+192];
    float a2 = redB[t] + redB[t+64] + redB[t+128] + redB[t+192];
    atomicAdd(&ws[HS + t],      a1);
    atomicAdd(&ws[HS + 64 + t], a2);
  }
}

// ================= K3: k_final (R22 verbatim) =================
__global__ __launch_bounds__(512)
void k_final(const float* __restrict__ x,
             const float* __restrict__ hbuf, const float* __restrict__ ws,
             const float* __restrict__ no_w, const float* __restrict__ no_b,
             const float* __restrict__ no_ms,
             const float* __restrict__ pn_w, const float* __restrict__ pn_b,
             const float* __restrict__ pn_ms,
             float* __restrict__ out){
  __shared__ __align__(16) float W1[4096];
  __shared__ __align__(16) float W2[4096];
  __shared__ __align__(16) float PW1[4096];
  __shared__ __align__(16) float fbs[260];
  __shared__ __align__(16) float hs[GSIZE][68];
  __shared__ __align__(16) float hn[GSIZE][68];
  __shared__ __align__(16) float ts[GSIZE][68];
  __shared__ float A2s[DH], C2s[DH];
  __shared__ float a3[DH], c3[DH];
  __shared__ float scores[GSIZE], wsm[GSIZE];

  int t = threadIdx.x;
  int base = blockIdx.x * GSIZE;
  int c = t & 63, i0 = t >> 6;      // rows i0+8r, r=0..2

  {
    const float4* s1 = (const float4*)(ws + WT1);
    const float4* s2 = (const float4*)(ws + WT2);
    const float4* s3 = (const float4*)(ws + PWT1);
    #pragma unroll
    for(int it = 0; it < 2; ++it){
      int i = t + it*512;
      ((float4*)W1)[i]  = s1[i];
      ((float4*)W2)[i]  = s2[i];
      ((float4*)PW1)[i] = s3[i];
    }
    if(t < 257) fbs[t] = ws[FBo + t];
    if(t < DH){
      float a1 = ws[HS + t];
      float a2 = ws[HS + 64 + t];
      float mean = a1 * (1.0f / N_NODES);
      float ex2  = a2 * (1.0f / N_NODES);
      float cm   = mean * no_ms[t];
      float var  = ex2 - 2.f*cm*mean + cm*cm;
      float rstd = rsqrtf(var + EPSN);
      float a    = no_w[t] * rstd;
      A2s[t] = a; C2s[t] = no_b[t] - a*cm;
    }
  }
  __syncthreads();
  {
    float a2 = A2s[c];
    float c2 = C2s[c];
    #pragma unroll
    for(int r = 0; r < 3; ++r){
      int i = i0 + 8*r;
      float hvv = hbuf[(size_t)(base + i)*DH + c];
      hs[i][c] = hvv;
      hn[i][c] = a2*hvv + c2;
    }
  }
  __syncthreads();

  {
    float acc[3];
    #pragma unroll
    for(int r = 0; r < 3; ++r) acc[r] = fbs[c];
    #pragma unroll 16
    for(int k = 0; k < DH; ++k){
      float w = W1[k*DH + c];
      #pragma unroll
      for(int r = 0; r < 3; ++r) acc[r] = fmaf(hn[i0 + 8*r][k], w, acc[r]);
    }
    #pragma unroll
    for(int r = 0; r < 3; ++r) ts[i0 + 8*r][c] = gelu_exact(acc[r]);
  }
  __syncthreads();

  {
    float acc[3];
    #pragma unroll
    for(int r = 0; r < 3; ++r) acc[r] = fbs[64 + c];
    #pragma unroll 16
    for(int k = 0; k < DH; ++k){
      float w = W2[k*DH + c];
      #pragma unroll
      for(int r = 0; r < 3; ++r) acc[r] = fmaf(ts[i0 + 8*r][k], w, acc[r]);
    }
    #pragma unroll
    for(int r = 0; r < 3; ++r) hs[i0 + 8*r][c] += acc[r];
  }
  __syncthreads();

  if(t < DH){
    float s1 = 0.f, s2 = 0.f;
    #pragma unroll
    for(int i = 0; i < GSIZE; i++){ float v = hs[i][t]; s1 += v; s2 += v*v; }
    float mean = s1 * (1.0f / GSIZE);
    float ex2  = s2 * (1.0f / GSIZE);
    float cm   = mean * pn_ms[t];
    float var  = ex2 - 2.f*cm*mean + cm*cm;
    float rstd = rsqrtf(var + EPSN);
    float a    = pn_w[t] * rstd;
    a3[t] = a; c3[t] = pn_b[t] - a*cm;
  }
  __syncthreads();

  {
    float acc[3];
    #pragma unroll
    for(int r = 0; r < 3; ++r) acc[r] = fbs[128 + c];
    #pragma unroll 16
    for(int k = 0; k < DH; ++k){
      float w  = PW1[k*DH + c];
      float ak = a3[k], ck = c3[k];
      #pragma unroll
      for(int r = 0; r < 3; ++r){
        float hnv = fmaf(ak, hs[i0 + 8*r][k], ck);
        acc[r] = fmaf(hnv, w, acc[r]);
      }
    }
    #pragma unroll
    for(int r = 0; r < 3; ++r) ts[i0 + 8*r][c] = gelu_exact(acc[r]);
  }
  __syncthreads();

  if(t < GSIZE){
    const float4* tp = (const float4*)ts[t];
    const float4* wp = (const float4*)(fbs + 192);
    float s = fbs[256];
    #pragma unroll
    for(int q = 0; q < 16; ++q){
      float4 a = tp[q], b = wp[q];
      s += a.x*b.x + a.y*b.y + a.z*b.z + a.w*b.w;
    }
    scores[t] = s;
  }
  __syncthreads();
  if(t < GSIZE){
    float mx = -1e30f;
    #pragma unroll
    for(int j = 0; j < GSIZE; j++) mx = fmaxf(mx, scores[j]);
    float sum = 0.f;
    #pragma unroll
    for(int j = 0; j < GSIZE; j++) sum += __expf(scores[j] - mx);
    wsm[t] = __expf(scores[t] - mx) / (sum + 1e-16f);
  }
  __syncthreads();
  if(t < DIN){
    float s = 0.f;
    #pragma unroll 8
    for(int i = 0; i < GSIZE; i++) s += wsm[i] * x[(size_t)(base+i)*DIN + t];
    out[(size_t)blockIdx.x*DIN + t] = s;
  }
}

extern "C" void kernel_launch(void* const* d_in, const int* in_sizes, int n_in,
                              void* d_out, int out_size, void* d_ws, size_t ws_size,
                              hipStream_t stream){
  (void)in_sizes; (void)n_in; (void)out_size; (void)ws_size;
  const float* x    = (const float*)d_in[0];
  const float* nq_w = (const float*)d_in[4];
  const float* nq_b = (const float*)d_in[5];
  const float* nq_ms= (const float*)d_in[6];
  const float* wq   = (const float*)d_in[7];
  const float* bq   = (const float*)d_in[8];
  const float* wk   = (const float*)d_in[9];
  const float* bk   = (const float*)d_in[10];
  const float* wv   = (const float*)d_in[11];
  const float* bv   = (const float*)d_in[12];
  const float* no_w = (const float*)d_in[13];
  const float* no_b = (const float*)d_in[14];
  const float* no_ms= (const float*)d_in[15];
  const float* o_w1 = (const float*)d_in[16];
  const float* o_b1 = (const float*)d_in[17];
  const float* o_w2 = (const float*)d_in[18];
  const float* o_b2 = (const float*)d_in[19];
  const float* pn_w = (const float*)d_in[20];
  const float* pn_b = (const float*)d_in[21];
  const float* pn_ms= (const float*)d_in[22];
  const float* p_w1 = (const float*)d_in[23];
  const float* p_b1 = (const float*)d_in[24];
  const float* p_w2 = (const float*)d_in[25];
  const float* p_b2 = (const float*)d_in[26];

  float* ws    = (float*)d_ws;
  float* hcomb = ws + HCF;

  // zero XS + HS + hcomb (atomic accumulators; ws is poisoned)
  hipMemsetAsync(d_ws, 0, (size_t)(384 + N_NODES*DH)*sizeof(float), stream);
  k_pre<<<207, 256, 0, stream>>>(x, o_w1, o_w2, p_w1, o_b1, o_b2, p_b1, p_w2, p_b2,
                                 wq, wk, wv, ws);
  k_attn4<<<2048, 256, 0, stream>>>(x, bq, bk, bv, nq_w, nq_b, nq_ms, ws, hcomb);
  k_hfix<<<192, 256, 0, stream>>>(x, ws, hcomb);
  k_final<<<NGRAPH, 512, 0, stream>>>(x, hcomb, ws, no_w, no_b, no_ms,
                                      pn_w, pn_b, pn_ms, (float*)d_out);
}